// Round 2
// baseline (1215.735 us; speedup 1.0000x reference)
//
#include <hip/hip_runtime.h>
#include <hip/hip_bf16.h>

// Problem: B=8, C=512, N=G*H*W=4096. All f32 in/out.
//   er = QrQr^T - QiQi^T ; ei = QrQi^T + (QrQi^T)^T   (B x C x C)
//   A  = softmax_row((rowmax(er)-er)^2 + (rowmax(ei)-ei)^2)   [near one-hot!]
//   out = stack(g*A@Qr + xr, g*A@Qi + xi)
// Stage 1 must be ~f32-accurate (softmax argument spans ~7e5; bf16 would flip
// the argmax) -> f32 vector FMA. Stage 3 tolerance is loose -> bf16 MFMA.
#define B_ 8
#define C_ 512
#define N_ 4096
#define BK 32

typedef __bf16 bf16x8 __attribute__((ext_vector_type(8)));
typedef float f32x4 __attribute__((ext_vector_type(4)));

__device__ __forceinline__ f32x4 mfma16(bf16x8 a, bf16x8 b, f32x4 c) {
    // A[m=lane&15][k=quad*8+j]; B[k=quad*8+j][n=lane&15]; D: col=lane&15, row=quad*4+reg
    return __builtin_amdgcn_mfma_f32_16x16x32_bf16(a, b, c, 0, 0, 0);
}

// pack two f32 -> bf16x2 word (RNE), lo in low half
__device__ __forceinline__ unsigned f2bf2(float lo, float hi) {
    unsigned ul = __float_as_uint(lo);
    ul += 0x7FFFu + ((ul >> 16) & 1u);
    unsigned uh = __float_as_uint(hi);
    uh += 0x7FFFu + ((uh >> 16) & 1u);
    return (ul >> 16) | (uh & 0xFFFF0000u);
}

// ---------------- Stage 1: energy (er, ei), f32 vector FMA -------------------
// grid (dt=8, ct=8, b=8), block 256 = 16x16 threads, 4x4 outputs/thread.
// LDS tiles transposed [k][row] (pad 68 -> 16B-aligned f32x4 reads, <=2-way).
__global__ __launch_bounds__(256, 2) void energy_kernel(const float* __restrict__ x,
                                                        float* __restrict__ er,
                                                        float* __restrict__ ei) {
    __shared__ float Ar[BK][68];
    __shared__ float Ai[BK][68];
    __shared__ float Brs[BK][68];
    __shared__ float Bis[BK][68];
    const int b = blockIdx.z, ct = blockIdx.y, dt = blockIdx.x;
    const int t = threadIdx.x;
    const int tx = t & 15, ty = t >> 4;
    const int row = t & 63, kq = t >> 6;   // staging: row 0..63, wave = k-octet

    const float* qr = x + (size_t)b * C_ * N_;
    const float* qi = qr + (size_t)B_ * C_ * N_;
    const float* ag = qr + (size_t)(ct * 64 + row) * N_ + kq * 8;
    const float* cg = qi + (size_t)(ct * 64 + row) * N_ + kq * 8;
    const float* bg = qr + (size_t)(dt * 64 + row) * N_ + kq * 8;
    const float* dg = qi + (size_t)(dt * 64 + row) * N_ + kq * 8;

    float rr[4][4] = {}, ii2[4][4] = {}, ri[4][4] = {}, ir[4][4] = {};

    for (int k0 = 0; k0 < N_; k0 += BK) {
        const f32x4 a0 = *(const f32x4*)(ag + k0);
        const f32x4 a1 = *(const f32x4*)(ag + k0 + 4);
        const f32x4 c0 = *(const f32x4*)(cg + k0);
        const f32x4 c1 = *(const f32x4*)(cg + k0 + 4);
        const f32x4 b0 = *(const f32x4*)(bg + k0);
        const f32x4 b1 = *(const f32x4*)(bg + k0 + 4);
        const f32x4 d0 = *(const f32x4*)(dg + k0);
        const f32x4 d1 = *(const f32x4*)(dg + k0 + 4);
        __syncthreads();   // previous iteration's LDS reads done
#pragma unroll
        for (int j = 0; j < 4; ++j) {
            Ar[kq * 8 + j][row] = a0[j];
            Ar[kq * 8 + 4 + j][row] = a1[j];
            Ai[kq * 8 + j][row] = c0[j];
            Ai[kq * 8 + 4 + j][row] = c1[j];
            Brs[kq * 8 + j][row] = b0[j];
            Brs[kq * 8 + 4 + j][row] = b1[j];
            Bis[kq * 8 + j][row] = d0[j];
            Bis[kq * 8 + 4 + j][row] = d1[j];
        }
        __syncthreads();
#pragma unroll 4
        for (int k = 0; k < BK; ++k) {
            const f32x4 av = *(const f32x4*)&Ar[k][ty * 4];
            const f32x4 iv = *(const f32x4*)&Ai[k][ty * 4];
            const f32x4 bv = *(const f32x4*)&Brs[k][tx * 4];
            const f32x4 dv = *(const f32x4*)&Bis[k][tx * 4];
#pragma unroll
            for (int i = 0; i < 4; ++i)
#pragma unroll
                for (int j = 0; j < 4; ++j) {
                    rr[i][j] += av[i] * bv[j];
                    ii2[i][j] += iv[i] * dv[j];
                    ri[i][j] += av[i] * dv[j];
                    ir[i][j] += iv[i] * bv[j];
                }
        }
    }

#pragma unroll
    for (int i = 0; i < 4; ++i) {
        const int c = ct * 64 + ty * 4 + i;
        const size_t base = ((size_t)(b * C_ + c)) * C_ + dt * 64 + tx * 4;
        f32x4 e, f;
#pragma unroll
        for (int j = 0; j < 4; ++j) {
            e[j] = rr[i][j] - ii2[i][j];
            f[j] = ri[i][j] + ir[i][j];
        }
        *(f32x4*)(er + base) = e;
        *(f32x4*)(ei + base) = f;
    }
}

// ---------------- Stage 2: softmax over squared magnitude --------------------
__device__ __forceinline__ float waveMax(float v) {
#pragma unroll
    for (int off = 32; off > 0; off >>= 1) v = fmaxf(v, __shfl_xor(v, off));
    return v;
}
__device__ __forceinline__ float waveSum(float v) {
#pragma unroll
    for (int off = 32; off > 0; off >>= 1) v += __shfl_xor(v, off);
    return v;
}

// grid (c=512, b=8), block 256 -> one row of 512 per block, 2 elems/thread.
__global__ __launch_bounds__(256) void softmax_kernel(const float* __restrict__ er,
                                                      const float* __restrict__ ei,
                                                      __bf16* __restrict__ att) {
    __shared__ float buf[4];
    const int b = blockIdx.y, c = blockIdx.x, t = threadIdx.x;
    const int wave = t >> 6, lane = t & 63;
    const size_t rbase = ((size_t)(b * C_ + c)) * C_;

    const float er0 = er[rbase + t], er1 = er[rbase + t + 256];
    const float ei0 = ei[rbase + t], ei1 = ei[rbase + t + 256];

    float v = waveMax(fmaxf(er0, er1));
    if (lane == 0) buf[wave] = v;
    __syncthreads();
    const float mer = fmaxf(fmaxf(buf[0], buf[1]), fmaxf(buf[2], buf[3]));
    __syncthreads();

    v = waveMax(fmaxf(ei0, ei1));
    if (lane == 0) buf[wave] = v;
    __syncthreads();
    const float mei = fmaxf(fmaxf(buf[0], buf[1]), fmaxf(buf[2], buf[3]));
    __syncthreads();

    const float a0 = mer - er0, c0 = mei - ei0;
    const float a1 = mer - er1, c1 = mei - ei1;
    const float t0 = a0 * a0 + c0 * c0;
    const float t1 = a1 * a1 + c1 * c1;

    v = waveMax(fmaxf(t0, t1));
    if (lane == 0) buf[wave] = v;
    __syncthreads();
    const float mt = fmaxf(fmaxf(buf[0], buf[1]), fmaxf(buf[2], buf[3]));
    __syncthreads();

    const float e0 = expf(t0 - mt), e1 = expf(t1 - mt);
    v = waveSum(e0 + e1);
    if (lane == 0) buf[wave] = v;
    __syncthreads();
    const float s = buf[0] + buf[1] + buf[2] + buf[3];
    const float inv = 1.0f / s;

    att[rbase + t] = (__bf16)(e0 * inv);
    att[rbase + t + 256] = (__bf16)(e1 * inv);
}

// ---------------- Stage 3: out = g * (A @ Q) + x, bf16 MFMA ------------------
// grid (nt=64, ct=8, b=8), block 256. 64(c) x 64(n) tile, K=512 over d.
// A (attention, bf16) loaded direct from global; Q tile f32->bf16 converted
// in-register and transposed into LDS as k-pair-packed words:
//   word[(n)*20 + k/2] = {bf16 q[k][n], bf16 q[k+1][n]}   (stride 20 words)
// writes: <=2-way (free); reads: ds_read_b128, 16B-aligned (80n+16q), uniform
// 8 lanes per 4-bank group = b128 BW floor.
__global__ __launch_bounds__(256) void out_kernel(const float* __restrict__ x,
                                                  const __bf16* __restrict__ att,
                                                  const float* __restrict__ gamma,
                                                  float* __restrict__ out) {
    __shared__ __align__(16) unsigned Lr[64 * 20];
    __shared__ __align__(16) unsigned Li[64 * 20];
    const int b = blockIdx.z, ct = blockIdx.y, nt = blockIdx.x;
    const int t = threadIdx.x, lane = t & 63, wave = t >> 6;
    const int m = lane & 15, quad = lane >> 4;

    const float* qr = x + (size_t)b * C_ * N_;
    const float* qi = qr + (size_t)B_ * C_ * N_;
    const int c = ct * 64 + wave * 16 + m;
    const __bf16* arow = att + ((size_t)(b * C_ + c)) * C_ + quad * 8;

    const int kp = t & 15;        // k-pair index: k = 2kp, 2kp+1
    const int n4 = (t >> 4) * 4;  // n group 0,4,..,60
    const int n0 = nt * 64;

    const f32x4 zero = {0.f, 0.f, 0.f, 0.f};
    f32x4 accr[4] = {zero, zero, zero, zero};
    f32x4 acci[4] = {zero, zero, zero, zero};

    for (int kk = 0; kk < C_; kk += 32) {
        const f32x4 r0 = *(const f32x4*)(qr + (size_t)(kk + 2 * kp) * N_ + n0 + n4);
        const f32x4 r1 = *(const f32x4*)(qr + (size_t)(kk + 2 * kp + 1) * N_ + n0 + n4);
        const f32x4 i0 = *(const f32x4*)(qi + (size_t)(kk + 2 * kp) * N_ + n0 + n4);
        const f32x4 i1 = *(const f32x4*)(qi + (size_t)(kk + 2 * kp + 1) * N_ + n0 + n4);
        const bf16x8 a = *(const bf16x8*)(arow + kk);
        __syncthreads();   // previous iteration's LDS reads done
#pragma unroll
        for (int u = 0; u < 4; ++u) {
            Lr[(n4 + u) * 20 + kp] = f2bf2(r0[u], r1[u]);
            Li[(n4 + u) * 20 + kp] = f2bf2(i0[u], i1[u]);
        }
        __syncthreads();
#pragma unroll
        for (int s = 0; s < 4; ++s) {
            const bf16x8 br = *(const bf16x8*)(&Lr[(s * 16 + m) * 20 + quad * 4]);
            const bf16x8 bi = *(const bf16x8*)(&Li[(s * 16 + m) * 20 + quad * 4]);
            accr[s] = mfma16(a, br, accr[s]);
            acci[s] = mfma16(a, bi, acci[s]);
        }
    }

    const float g = gamma[0];
    float* outr = out + (size_t)b * C_ * N_;
    float* outi = outr + (size_t)B_ * C_ * N_;
#pragma unroll
    for (int s = 0; s < 4; ++s)
#pragma unroll
        for (int r = 0; r < 4; ++r) {
            const int row = quad * 4 + r;
            const int cc = ct * 64 + wave * 16 + row;
            const int nn = n0 + s * 16 + m;
            const size_t ix = (size_t)cc * N_ + nn;
            outr[ix] = g * accr[s][r] + qr[ix];
            outi[ix] = g * acci[s][r] + qi[ix];
        }
}

// -----------------------------------------------------------------------------
extern "C" void kernel_launch(void* const* d_in, const int* in_sizes, int n_in,
                              void* d_out, int out_size, void* d_ws, size_t ws_size,
                              hipStream_t stream) {
    const float* x = (const float*)d_in[0];
    const float* gamma = (const float*)d_in[1];
    float* out = (float*)d_out;

    // workspace: er (8.4 MB f32) | ei (8.4 MB f32) | att (4.2 MB bf16) = 21 MB
    float* er = (float*)d_ws;
    float* ei = er + (size_t)B_ * C_ * C_;
    __bf16* att = (__bf16*)(ei + (size_t)B_ * C_ * C_);

    energy_kernel<<<dim3(8, 8, 8), 256, 0, stream>>>(x, er, ei);
    softmax_kernel<<<dim3(C_, B_), 256, 0, stream>>>(er, ei, att);
    out_kernel<<<dim3(64, 8, 8), 256, 0, stream>>>(x, att, gamma, out);
}

// Round 3
// 911.729 us; speedup vs baseline: 1.3334x; 1.3334x over previous
//
#include <hip/hip_runtime.h>
#include <hip/hip_bf16.h>

// Problem: B=8, C=512, N=G*H*W=4096. All f32 in/out.
//   er = QrQr^T - QiQi^T ; ei = QrQi^T + (QrQi^T)^T   (B x C x C) -- BOTH SYMMETRIC
//   A  = softmax_row((rowmax(er)-er)^2 + (rowmax(ei)-ei)^2)   [near one-hot]
//   out = stack(g*A@Qr + xr, g*A@Qi + xi)
// Stage 1 must be ~f32-accurate (softmax arg spans ~1e6; bf16 flips the argmax)
// -> f32 vector FMA, upper-triangle tiles only, split-K=4 for occupancy.
// Split-K partials live in d_out (134 MB, free until stage 3). Stage 3: bf16 MFMA.
#define B_ 8
#define C_ 512
#define N_ 4096
#define BK 32
#define NSPLIT 4
#define KCH (N_ / NSPLIT)
static const size_t PS = (size_t)B_ * C_ * C_;  // floats per partial buffer

typedef __bf16 bf16x8 __attribute__((ext_vector_type(8)));
typedef float f32x4 __attribute__((ext_vector_type(4)));

__device__ __constant__ unsigned char CTAB[36] = {0,0,0,0,0,0,0,0, 1,1,1,1,1,1,1,
                                                  2,2,2,2,2,2, 3,3,3,3,3, 4,4,4,4, 5,5,5, 6,6, 7};
__device__ __constant__ unsigned char DTAB[36] = {0,1,2,3,4,5,6,7, 1,2,3,4,5,6,7,
                                                  2,3,4,5,6,7, 3,4,5,6,7, 4,5,6,7, 5,6,7, 6,7, 7};

__device__ __forceinline__ f32x4 mfma16(bf16x8 a, bf16x8 b, f32x4 c) {
    // A[m=lane&15][k=quad*8+j]; B[k=quad*8+j][n=lane&15]; D: col=lane&15, row=quad*4+reg
    return __builtin_amdgcn_mfma_f32_16x16x32_bf16(a, b, c, 0, 0, 0);
}

// pack two f32 -> bf16x2 word (RNE), lo in low half
__device__ __forceinline__ unsigned f2bf2(float lo, float hi) {
    unsigned ul = __float_as_uint(lo);
    ul += 0x7FFFu + ((ul >> 16) & 1u);
    unsigned uh = __float_as_uint(hi);
    uh += 0x7FFFu + ((uh >> 16) & 1u);
    return (ul >> 16) | (uh & 0xFFFF0000u);
}

// ---------------- Stage 1: energy partials, f32 vector FMA -------------------
// grid (tile=36, split=4, b=8), block 256 = 16x16 threads, 4x4 outputs/thread.
// Tile (ct,dt) ct<=dt of the 64x64 decomposition; mirror tile written by
// register-transpose. K-chunk of 1024 per split; partial sums -> pbuf in d_out.
__global__ __launch_bounds__(256, 4) void energy_kernel(const float* __restrict__ x,
                                                        float* __restrict__ pbuf) {
    __shared__ float Ar[BK][68];
    __shared__ float Ai[BK][68];
    __shared__ float Brs[BK][68];
    __shared__ float Bis[BK][68];
    const int b = blockIdx.z, sp = blockIdx.y;
    const int ct = CTAB[blockIdx.x], dt = DTAB[blockIdx.x];
    const int t = threadIdx.x;
    const int tx = t & 15, ty = t >> 4;
    const int row = t & 63, kq = t >> 6;   // staging: row 0..63, wave = k-octet

    const float* qr = x + (size_t)b * C_ * N_;
    const float* qi = qr + (size_t)B_ * C_ * N_;
    const int kbase = sp * KCH;
    const float* ag = qr + (size_t)(ct * 64 + row) * N_ + kbase + kq * 8;
    const float* cg = qi + (size_t)(ct * 64 + row) * N_ + kbase + kq * 8;
    const float* bg = qr + (size_t)(dt * 64 + row) * N_ + kbase + kq * 8;
    const float* dg = qi + (size_t)(dt * 64 + row) * N_ + kbase + kq * 8;

    float rr[4][4] = {}, ii2[4][4] = {}, ri[4][4] = {}, ir[4][4] = {};

    for (int k0 = 0; k0 < KCH; k0 += BK) {
        const f32x4 a0 = *(const f32x4*)(ag + k0);
        const f32x4 a1 = *(const f32x4*)(ag + k0 + 4);
        const f32x4 c0 = *(const f32x4*)(cg + k0);
        const f32x4 c1 = *(const f32x4*)(cg + k0 + 4);
        const f32x4 b0 = *(const f32x4*)(bg + k0);
        const f32x4 b1 = *(const f32x4*)(bg + k0 + 4);
        const f32x4 d0 = *(const f32x4*)(dg + k0);
        const f32x4 d1 = *(const f32x4*)(dg + k0 + 4);
        __syncthreads();   // previous iteration's LDS reads done
#pragma unroll
        for (int j = 0; j < 4; ++j) {
            Ar[kq * 8 + j][row] = a0[j];
            Ar[kq * 8 + 4 + j][row] = a1[j];
            Ai[kq * 8 + j][row] = c0[j];
            Ai[kq * 8 + 4 + j][row] = c1[j];
            Brs[kq * 8 + j][row] = b0[j];
            Brs[kq * 8 + 4 + j][row] = b1[j];
            Bis[kq * 8 + j][row] = d0[j];
            Bis[kq * 8 + 4 + j][row] = d1[j];
        }
        __syncthreads();
#pragma unroll 4
        for (int k = 0; k < BK; ++k) {
            const f32x4 av = *(const f32x4*)&Ar[k][ty * 4];
            const f32x4 iv = *(const f32x4*)&Ai[k][ty * 4];
            const f32x4 bv = *(const f32x4*)&Brs[k][tx * 4];
            const f32x4 dv = *(const f32x4*)&Bis[k][tx * 4];
#pragma unroll
            for (int i = 0; i < 4; ++i)
#pragma unroll
                for (int j = 0; j < 4; ++j) {
                    rr[i][j] += av[i] * bv[j];
                    ii2[i][j] += iv[i] * dv[j];
                    ri[i][j] += av[i] * dv[j];
                    ir[i][j] += iv[i] * bv[j];
                }
        }
    }

    float e[4][4], f[4][4];
#pragma unroll
    for (int i = 0; i < 4; ++i)
#pragma unroll
        for (int j = 0; j < 4; ++j) {
            e[i][j] = rr[i][j] - ii2[i][j];
            f[i][j] = ri[i][j] + ir[i][j];
        }

    float* per = pbuf + (size_t)(2 * sp) * PS + (size_t)b * C_ * C_;
    float* pei = per + PS;
#pragma unroll
    for (int i = 0; i < 4; ++i) {
        const size_t base = (size_t)(ct * 64 + ty * 4 + i) * C_ + dt * 64 + tx * 4;
        f32x4 ev, fv;
#pragma unroll
        for (int j = 0; j < 4; ++j) { ev[j] = e[i][j]; fv[j] = f[i][j]; }
        *(f32x4*)(per + base) = ev;
        *(f32x4*)(pei + base) = fv;
    }
    if (ct != dt) {  // mirror tile, register-transposed
#pragma unroll
        for (int j = 0; j < 4; ++j) {
            const size_t base = (size_t)(dt * 64 + tx * 4 + j) * C_ + ct * 64 + ty * 4;
            f32x4 ev, fv;
#pragma unroll
            for (int i = 0; i < 4; ++i) { ev[i] = e[i][j]; fv[i] = f[i][j]; }
            *(f32x4*)(per + base) = ev;
            *(f32x4*)(pei + base) = fv;
        }
    }
}

// ---------------- Stage 2: fold split-K partials + softmax -------------------
__device__ __forceinline__ float waveMax(float v) {
#pragma unroll
    for (int off = 32; off > 0; off >>= 1) v = fmaxf(v, __shfl_xor(v, off));
    return v;
}
__device__ __forceinline__ float waveSum(float v) {
#pragma unroll
    for (int off = 32; off > 0; off >>= 1) v += __shfl_xor(v, off);
    return v;
}

// grid (c=512, b=8), block 256 -> one row of 512 per block, 2 elems/thread.
__global__ __launch_bounds__(256) void softmax_kernel(const float* __restrict__ pbuf,
                                                      __bf16* __restrict__ att) {
    __shared__ float buf[4];
    const int b = blockIdx.y, c = blockIdx.x, t = threadIdx.x;
    const int wave = t >> 6, lane = t & 63;
    const size_t rbase = ((size_t)(b * C_ + c)) * C_;

    float er0 = 0.f, er1 = 0.f, ei0 = 0.f, ei1 = 0.f;
#pragma unroll
    for (int s = 0; s < NSPLIT; ++s) {
        const float* per = pbuf + (size_t)(2 * s) * PS;
        const float* pei = per + PS;
        er0 += per[rbase + t];
        er1 += per[rbase + t + 256];
        ei0 += pei[rbase + t];
        ei1 += pei[rbase + t + 256];
    }

    float v = waveMax(fmaxf(er0, er1));
    if (lane == 0) buf[wave] = v;
    __syncthreads();
    const float mer = fmaxf(fmaxf(buf[0], buf[1]), fmaxf(buf[2], buf[3]));
    __syncthreads();

    v = waveMax(fmaxf(ei0, ei1));
    if (lane == 0) buf[wave] = v;
    __syncthreads();
    const float mei = fmaxf(fmaxf(buf[0], buf[1]), fmaxf(buf[2], buf[3]));
    __syncthreads();

    const float a0 = mer - er0, c0 = mei - ei0;
    const float a1 = mer - er1, c1 = mei - ei1;
    const float t0 = a0 * a0 + c0 * c0;
    const float t1 = a1 * a1 + c1 * c1;

    v = waveMax(fmaxf(t0, t1));
    if (lane == 0) buf[wave] = v;
    __syncthreads();
    const float mt = fmaxf(fmaxf(buf[0], buf[1]), fmaxf(buf[2], buf[3]));
    __syncthreads();

    const float e0 = expf(t0 - mt), e1 = expf(t1 - mt);
    v = waveSum(e0 + e1);
    if (lane == 0) buf[wave] = v;
    __syncthreads();
    const float s = buf[0] + buf[1] + buf[2] + buf[3];
    const float inv = 1.0f / s;

    att[rbase + t] = (__bf16)(e0 * inv);
    att[rbase + t + 256] = (__bf16)(e1 * inv);
}

// ---------------- Stage 3: out = g * (A @ Q) + x, bf16 MFMA ------------------
// grid (nt=64, ct=8, b=8), block 256. 64(c) x 64(n) tile, K=512 over d.
// A (attention, bf16) direct from global; Q tile f32->bf16 converted in-register
// and transposed into LDS as k-pair-packed words (stride 20 -> conflict-free).
__global__ __launch_bounds__(256) void out_kernel(const float* __restrict__ x,
                                                  const __bf16* __restrict__ att,
                                                  const float* __restrict__ gamma,
                                                  float* __restrict__ out) {
    __shared__ __align__(16) unsigned Lr[64 * 20];
    __shared__ __align__(16) unsigned Li[64 * 20];
    const int b = blockIdx.z, ct = blockIdx.y, nt = blockIdx.x;
    const int t = threadIdx.x, lane = t & 63, wave = t >> 6;
    const int m = lane & 15, quad = lane >> 4;

    const float* qr = x + (size_t)b * C_ * N_;
    const float* qi = qr + (size_t)B_ * C_ * N_;
    const int c = ct * 64 + wave * 16 + m;
    const __bf16* arow = att + ((size_t)(b * C_ + c)) * C_ + quad * 8;

    const int kp = t & 15;        // k-pair index: k = 2kp, 2kp+1
    const int n4 = (t >> 4) * 4;  // n group 0,4,..,60
    const int n0 = nt * 64;

    const f32x4 zero = {0.f, 0.f, 0.f, 0.f};
    f32x4 accr[4] = {zero, zero, zero, zero};
    f32x4 acci[4] = {zero, zero, zero, zero};

    for (int kk = 0; kk < C_; kk += 32) {
        const f32x4 r0 = *(const f32x4*)(qr + (size_t)(kk + 2 * kp) * N_ + n0 + n4);
        const f32x4 r1 = *(const f32x4*)(qr + (size_t)(kk + 2 * kp + 1) * N_ + n0 + n4);
        const f32x4 i0 = *(const f32x4*)(qi + (size_t)(kk + 2 * kp) * N_ + n0 + n4);
        const f32x4 i1 = *(const f32x4*)(qi + (size_t)(kk + 2 * kp + 1) * N_ + n0 + n4);
        const bf16x8 a = *(const bf16x8*)(arow + kk);
        __syncthreads();   // previous iteration's LDS reads done
#pragma unroll
        for (int u = 0; u < 4; ++u) {
            Lr[(n4 + u) * 20 + kp] = f2bf2(r0[u], r1[u]);
            Li[(n4 + u) * 20 + kp] = f2bf2(i0[u], i1[u]);
        }
        __syncthreads();
#pragma unroll
        for (int s = 0; s < 4; ++s) {
            const bf16x8 br = *(const bf16x8*)(&Lr[(s * 16 + m) * 20 + quad * 4]);
            const bf16x8 bi = *(const bf16x8*)(&Li[(s * 16 + m) * 20 + quad * 4]);
            accr[s] = mfma16(a, br, accr[s]);
            acci[s] = mfma16(a, bi, acci[s]);
        }
    }

    const float g = gamma[0];
    float* outr = out + (size_t)b * C_ * N_;
    float* outi = outr + (size_t)B_ * C_ * N_;
#pragma unroll
    for (int s = 0; s < 4; ++s)
#pragma unroll
        for (int r = 0; r < 4; ++r) {
            const int row = quad * 4 + r;
            const int cc = ct * 64 + wave * 16 + row;
            const int nn = n0 + s * 16 + m;
            const size_t ix = (size_t)cc * N_ + nn;
            outr[ix] = g * accr[s][r] + qr[ix];
            outi[ix] = g * acci[s][r] + qi[ix];
        }
}

// -----------------------------------------------------------------------------
extern "C" void kernel_launch(void* const* d_in, const int* in_sizes, int n_in,
                              void* d_out, int out_size, void* d_ws, size_t ws_size,
                              hipStream_t stream) {
    const float* x = (const float*)d_in[0];
    const float* gamma = (const float*)d_in[1];
    float* out = (float*)d_out;

    // Split-K partials (8 x 8.4 MB = 67 MB) live in d_out, which stage 3
    // overwrites afterwards. ws holds only att (4.2 MB bf16).
    float* pbuf = out;
    __bf16* att = (__bf16*)d_ws;

    energy_kernel<<<dim3(36, NSPLIT, B_), 256, 0, stream>>>(x, pbuf);
    softmax_kernel<<<dim3(C_, B_), 256, 0, stream>>>(pbuf, att);
    out_kernel<<<dim3(64, 8, 8), 256, 0, stream>>>(x, att, gamma, out);
}

// Round 4
// 527.204 us; speedup vs baseline: 2.3060x; 1.7294x over previous
//
#include <hip/hip_runtime.h>
#include <hip/hip_bf16.h>

// Problem: B=8, C=512, N=G*H*W=4096. All f32 in/out.
//   er = QrQr^T - QiQi^T ; ei = QrQi^T + (QrQi^T)^T   (B x C x C) -- BOTH SYMMETRIC
//   A  = softmax_row((rowmax(er)-er)^2 + (rowmax(ei)-ei)^2)   [near one-hot]
//   out = stack(g*A@Qr + xr, g*A@Qi + xi)
// Stage 1: split-bf16 MFMA (x = xh + xl; x*y ~ xh*yh + xh*yl + xl*yh, err ~2^-18)
//   -> ~f32-accurate energies at bf16 MFMA rate. Upper-triangle 128x64 tiles,
//   split-K=4, partials in d_out. Stages 2/3 as before.
#define B_ 8
#define C_ 512
#define N_ 4096
#define BK 32
#define NSPLIT 4
#define KCH (N_ / NSPLIT)
static const size_t PS = (size_t)B_ * C_ * C_;  // floats per partial buffer

typedef __bf16 bf16x8 __attribute__((ext_vector_type(8)));
typedef float f32x4 __attribute__((ext_vector_type(4)));

// 20 upper-triangle jobs: ci in 0..3 (128-row c-tile), dj in 0..7 (64-col d-tile), dj >= 2*ci
__device__ __constant__ unsigned char JCI[20] = {0,0,0,0,0,0,0,0, 1,1,1,1,1,1, 2,2,2,2, 3,3};
__device__ __constant__ unsigned char JDJ[20] = {0,1,2,3,4,5,6,7, 2,3,4,5,6,7, 4,5,6,7, 6,7};

__device__ __forceinline__ f32x4 mfma16(bf16x8 a, bf16x8 b, f32x4 c) {
    // A[m=lane&15][k=quad*8+j]; B[n=lane&15][k=quad*8+j]; D: col=lane&15, row=quad*4+reg
    return __builtin_amdgcn_mfma_f32_16x16x32_bf16(a, b, c, 0, 0, 0);
}

// pack two f32 -> bf16x2 word (RNE), lo in low half
__device__ __forceinline__ unsigned f2bf2(float lo, float hi) {
    unsigned ul = __float_as_uint(lo);
    ul += 0x7FFFu + ((ul >> 16) & 1u);
    unsigned uh = __float_as_uint(hi);
    uh += 0x7FFFu + ((uh >> 16) & 1u);
    return (ul >> 16) | (uh & 0xFFFF0000u);
}

// split f32x4 -> hi (truncated bf16, exact remainder) + lo (RNE bf16 of remainder)
// hi words via v_perm byte-pack; remainder x - asfloat(x & 0xffff0000) is exact.
__device__ __forceinline__ void cvt_store4(const f32x4 v, __bf16* hp, __bf16* lp) {
    const unsigned u0 = __float_as_uint(v[0]), u1 = __float_as_uint(v[1]);
    const unsigned u2 = __float_as_uint(v[2]), u3 = __float_as_uint(v[3]);
    uint2 h, l;
    h.x = __builtin_amdgcn_perm(u1, u0, 0x07060302u);  // [u0.hi16 | u1.hi16]
    h.y = __builtin_amdgcn_perm(u3, u2, 0x07060302u);
    const float l0 = v[0] - __uint_as_float(u0 & 0xFFFF0000u);
    const float l1 = v[1] - __uint_as_float(u1 & 0xFFFF0000u);
    const float l2 = v[2] - __uint_as_float(u2 & 0xFFFF0000u);
    const float l3 = v[3] - __uint_as_float(u3 & 0xFFFF0000u);
    l.x = f2bf2(l0, l1);
    l.y = f2bf2(l2, l3);
    *(uint2*)hp = h;
    *(uint2*)lp = l;
}

// ---------------- Stage 1: energy partials via split-bf16 MFMA ---------------
// grid (job=20, split=4, b=8), block 256 (4 waves). Block tile 128(c) x 64(d);
// wave (wr,wc) owns 64x32 = 4x2 tiles of 16x16. Accumulators per tile:
//   accRR (qr.qr), accII (qi.qi), accEI (qr.qi + qi.qr  -- shared acc).
// LDS: hi/lo bf16 panels, stride 40 (80 B rows: 16B-aligned b128 frags, 2-way max).
__global__ __launch_bounds__(256, 2) void energy_kernel(const float* __restrict__ x,
                                                        float* __restrict__ pbuf) {
    __shared__ __align__(16) __bf16 Ah[128][40], Al[128][40], Chs[128][40], Cls[128][40];
    __shared__ __align__(16) __bf16 Bh[64][40], Bl[64][40], Dh[64][40], Dl[64][40];
    const int b = blockIdx.z, sp = blockIdx.y;
    const int cbase = JCI[blockIdx.x] * 128, dbase = JDJ[blockIdx.x] * 64;
    const int t = threadIdx.x, lane = t & 63, wave = t >> 6;
    const int m = lane & 15, quad = lane >> 4;
    const int wr = wave >> 1, wc = wave & 1;

    const float* qr = x + (size_t)b * C_ * N_;
    const float* qi = qr + (size_t)B_ * C_ * N_;
    const int kbase = sp * KCH;

    const int a_row = t >> 1, a_k = (t & 1) * 16;  // A-panel: 2 thr/row, 16-k halves
    const int b_row = t >> 2, b_k = (t & 3) * 8;   // B-panel: 4 thr/row, 8-k quarters
    const float* agr = qr + (size_t)(cbase + a_row) * N_ + kbase + a_k;
    const float* agi = qi + (size_t)(cbase + a_row) * N_ + kbase + a_k;
    const float* bgr = qr + (size_t)(dbase + b_row) * N_ + kbase + b_k;
    const float* bgi = qi + (size_t)(dbase + b_row) * N_ + kbase + b_k;

    f32x4 accRR[4][2] = {}, accII[4][2] = {}, accEI[4][2] = {};

    for (int k0 = 0; k0 < KCH; k0 += BK) {
        f32x4 va[4], vc[4], vb[2], vd[2];
#pragma unroll
        for (int u = 0; u < 4; ++u) {
            va[u] = *(const f32x4*)(agr + k0 + u * 4);
            vc[u] = *(const f32x4*)(agi + k0 + u * 4);
        }
#pragma unroll
        for (int u = 0; u < 2; ++u) {
            vb[u] = *(const f32x4*)(bgr + k0 + u * 4);
            vd[u] = *(const f32x4*)(bgi + k0 + u * 4);
        }
        __syncthreads();  // previous iteration's LDS reads done
#pragma unroll
        for (int u = 0; u < 4; ++u) {
            cvt_store4(va[u], &Ah[a_row][a_k + u * 4], &Al[a_row][a_k + u * 4]);
            cvt_store4(vc[u], &Chs[a_row][a_k + u * 4], &Cls[a_row][a_k + u * 4]);
        }
#pragma unroll
        for (int u = 0; u < 2; ++u) {
            cvt_store4(vb[u], &Bh[b_row][b_k + u * 4], &Bl[b_row][b_k + u * 4]);
            cvt_store4(vd[u], &Dh[b_row][b_k + u * 4], &Dl[b_row][b_k + u * 4]);
        }
        __syncthreads();

        bf16x8 fBh[2], fBl[2], fDh[2], fDl[2];
#pragma unroll
        for (int j = 0; j < 2; ++j) {
            const int row = wc * 32 + j * 16 + m;
            fBh[j] = *(const bf16x8*)&Bh[row][quad * 8];
            fBl[j] = *(const bf16x8*)&Bl[row][quad * 8];
            fDh[j] = *(const bf16x8*)&Dh[row][quad * 8];
            fDl[j] = *(const bf16x8*)&Dl[row][quad * 8];
        }
#pragma unroll
        for (int i = 0; i < 4; ++i) {
            const int row = wr * 64 + i * 16 + m;
            const bf16x8 fAh = *(const bf16x8*)&Ah[row][quad * 8];
            const bf16x8 fAl = *(const bf16x8*)&Al[row][quad * 8];
            const bf16x8 fCh = *(const bf16x8*)&Chs[row][quad * 8];
            const bf16x8 fCl = *(const bf16x8*)&Cls[row][quad * 8];
#pragma unroll
            for (int j = 0; j < 2; ++j) {
                accRR[i][j] = mfma16(fAh, fBh[j], accRR[i][j]);
                accRR[i][j] = mfma16(fAh, fBl[j], accRR[i][j]);
                accRR[i][j] = mfma16(fAl, fBh[j], accRR[i][j]);
                accII[i][j] = mfma16(fCh, fDh[j], accII[i][j]);
                accII[i][j] = mfma16(fCh, fDl[j], accII[i][j]);
                accII[i][j] = mfma16(fCl, fDh[j], accII[i][j]);
                accEI[i][j] = mfma16(fAh, fDh[j], accEI[i][j]);
                accEI[i][j] = mfma16(fAh, fDl[j], accEI[i][j]);
                accEI[i][j] = mfma16(fAl, fDh[j], accEI[i][j]);
                accEI[i][j] = mfma16(fCh, fBh[j], accEI[i][j]);
                accEI[i][j] = mfma16(fCh, fBl[j], accEI[i][j]);
                accEI[i][j] = mfma16(fCl, fBh[j], accEI[i][j]);
            }
        }
    }

    float* per = pbuf + (size_t)(2 * sp) * PS + (size_t)b * C_ * C_;
    float* pei = per + PS;
#pragma unroll
    for (int i = 0; i < 4; ++i)
#pragma unroll
        for (int j = 0; j < 2; ++j) {
            const int c0 = cbase + wr * 64 + i * 16 + quad * 4;  // 4-aligned
            const int d = dbase + wc * 32 + j * 16 + m;
            const f32x4 e = accRR[i][j] - accII[i][j];
            const f32x4 f = accEI[i][j];
#pragma unroll
            for (int r = 0; r < 4; ++r) {  // direct (coalesced over m)
                per[(size_t)(c0 + r) * C_ + d] = e[r];
                pei[(size_t)(c0 + r) * C_ + d] = f[r];
            }
            // mirror (lower triangle): row d, cols c0..c0+3, 16B vector store
            *(f32x4*)(per + (size_t)d * C_ + c0) = e;
            *(f32x4*)(pei + (size_t)d * C_ + c0) = f;
        }
}

// ---------------- Stage 2: fold split-K partials + softmax -------------------
__device__ __forceinline__ float waveMax(float v) {
#pragma unroll
    for (int off = 32; off > 0; off >>= 1) v = fmaxf(v, __shfl_xor(v, off));
    return v;
}
__device__ __forceinline__ float waveSum(float v) {
#pragma unroll
    for (int off = 32; off > 0; off >>= 1) v += __shfl_xor(v, off);
    return v;
}

// grid (c=512, b=8), block 256 -> one row of 512 per block, 2 elems/thread.
__global__ __launch_bounds__(256) void softmax_kernel(const float* __restrict__ pbuf,
                                                      __bf16* __restrict__ att) {
    __shared__ float buf[4];
    const int b = blockIdx.y, c = blockIdx.x, t = threadIdx.x;
    const int wave = t >> 6, lane = t & 63;
    const size_t rbase = ((size_t)(b * C_ + c)) * C_;

    float er0 = 0.f, er1 = 0.f, ei0 = 0.f, ei1 = 0.f;
#pragma unroll
    for (int s = 0; s < NSPLIT; ++s) {
        const float* per = pbuf + (size_t)(2 * s) * PS;
        const float* pei = per + PS;
        er0 += per[rbase + t];
        er1 += per[rbase + t + 256];
        ei0 += pei[rbase + t];
        ei1 += pei[rbase + t + 256];
    }

    float v = waveMax(fmaxf(er0, er1));
    if (lane == 0) buf[wave] = v;
    __syncthreads();
    const float mer = fmaxf(fmaxf(buf[0], buf[1]), fmaxf(buf[2], buf[3]));
    __syncthreads();

    v = waveMax(fmaxf(ei0, ei1));
    if (lane == 0) buf[wave] = v;
    __syncthreads();
    const float mei = fmaxf(fmaxf(buf[0], buf[1]), fmaxf(buf[2], buf[3]));
    __syncthreads();

    const float a0 = mer - er0, c0 = mei - ei0;
    const float a1 = mer - er1, c1 = mei - ei1;
    const float t0 = a0 * a0 + c0 * c0;
    const float t1 = a1 * a1 + c1 * c1;

    v = waveMax(fmaxf(t0, t1));
    if (lane == 0) buf[wave] = v;
    __syncthreads();
    const float mt = fmaxf(fmaxf(buf[0], buf[1]), fmaxf(buf[2], buf[3]));
    __syncthreads();

    const float e0 = expf(t0 - mt), e1 = expf(t1 - mt);
    v = waveSum(e0 + e1);
    if (lane == 0) buf[wave] = v;
    __syncthreads();
    const float s = buf[0] + buf[1] + buf[2] + buf[3];
    const float inv = 1.0f / s;

    att[rbase + t] = (__bf16)(e0 * inv);
    att[rbase + t + 256] = (__bf16)(e1 * inv);
}

// ---------------- Stage 3: out = g * (A @ Q) + x, bf16 MFMA ------------------
// grid (nt=64, ct=8, b=8), block 256. 64(c) x 64(n) tile, K=512 over d.
// A (attention, bf16) direct from global; Q tile f32->bf16 converted in-register
// and transposed into LDS as k-pair-packed words (stride 20 -> conflict-free).
__global__ __launch_bounds__(256) void out_kernel(const float* __restrict__ x,
                                                  const __bf16* __restrict__ att,
                                                  const float* __restrict__ gamma,
                                                  float* __restrict__ out) {
    __shared__ __align__(16) unsigned Lr[64 * 20];
    __shared__ __align__(16) unsigned Li[64 * 20];
    const int b = blockIdx.z, ct = blockIdx.y, nt = blockIdx.x;
    const int t = threadIdx.x, lane = t & 63, wave = t >> 6;
    const int m = lane & 15, quad = lane >> 4;

    const float* qr = x + (size_t)b * C_ * N_;
    const float* qi = qr + (size_t)B_ * C_ * N_;
    const int c = ct * 64 + wave * 16 + m;
    const __bf16* arow = att + ((size_t)(b * C_ + c)) * C_ + quad * 8;

    const int kp = t & 15;        // k-pair index: k = 2kp, 2kp+1
    const int n4 = (t >> 4) * 4;  // n group 0,4,..,60
    const int n0 = nt * 64;

    const f32x4 zero = {0.f, 0.f, 0.f, 0.f};
    f32x4 accr[4] = {zero, zero, zero, zero};
    f32x4 acci[4] = {zero, zero, zero, zero};

    for (int kk = 0; kk < C_; kk += 32) {
        const f32x4 r0 = *(const f32x4*)(qr + (size_t)(kk + 2 * kp) * N_ + n0 + n4);
        const f32x4 r1 = *(const f32x4*)(qr + (size_t)(kk + 2 * kp + 1) * N_ + n0 + n4);
        const f32x4 i0 = *(const f32x4*)(qi + (size_t)(kk + 2 * kp) * N_ + n0 + n4);
        const f32x4 i1 = *(const f32x4*)(qi + (size_t)(kk + 2 * kp + 1) * N_ + n0 + n4);
        const bf16x8 a = *(const bf16x8*)(arow + kk);
        __syncthreads();  // previous iteration's LDS reads done
#pragma unroll
        for (int u = 0; u < 4; ++u) {
            Lr[(n4 + u) * 20 + kp] = f2bf2(r0[u], r1[u]);
            Li[(n4 + u) * 20 + kp] = f2bf2(i0[u], i1[u]);
        }
        __syncthreads();
#pragma unroll
        for (int s = 0; s < 4; ++s) {
            const bf16x8 br = *(const bf16x8*)(&Lr[(s * 16 + m) * 20 + quad * 4]);
            const bf16x8 bi = *(const bf16x8*)(&Li[(s * 16 + m) * 20 + quad * 4]);
            accr[s] = mfma16(a, br, accr[s]);
            acci[s] = mfma16(a, bi, acci[s]);
        }
    }

    const float g = gamma[0];
    float* outr = out + (size_t)b * C_ * N_;
    float* outi = outr + (size_t)B_ * C_ * N_;
#pragma unroll
    for (int s = 0; s < 4; ++s)
#pragma unroll
        for (int r = 0; r < 4; ++r) {
            const int row = quad * 4 + r;
            const int cc = ct * 64 + wave * 16 + row;
            const int nn = n0 + s * 16 + m;
            const size_t ix = (size_t)cc * N_ + nn;
            outr[ix] = g * accr[s][r] + qr[ix];
            outi[ix] = g * acci[s][r] + qi[ix];
        }
}

// -----------------------------------------------------------------------------
extern "C" void kernel_launch(void* const* d_in, const int* in_sizes, int n_in,
                              void* d_out, int out_size, void* d_ws, size_t ws_size,
                              hipStream_t stream) {
    const float* x = (const float*)d_in[0];
    const float* gamma = (const float*)d_in[1];
    float* out = (float*)d_out;

    // Split-K partials (2*NSPLIT x 8.4 MB = 67 MB) live in d_out (134 MB),
    // which stage 3 overwrites afterwards. ws holds only att (4.2 MB bf16).
    float* pbuf = out;
    __bf16* att = (__bf16*)d_ws;

    energy_kernel<<<dim3(20, NSPLIT, B_), 256, 0, stream>>>(x, pbuf);
    softmax_kernel<<<dim3(C_, B_), 256, 0, stream>>>(pbuf, att);
    out_kernel<<<dim3(64, 8, 8), 256, 0, stream>>>(x, att, gamma, out);
}